// Round 3
// baseline (226.756 us; speedup 1.0000x reference)
//
#include <hip/hip_runtime.h>
#include <hip/hip_fp16.h>

#define B_   8
#define CIN  256
#define T_   4096
#define TP   4097    // padded T (row 0 = zeros, row t+1 = x[t])
#define CO   256
#define O4   1024
#define NN   32768   // B_*T_
#define NCH  128     // chunks along T
#define CL   32      // chunk length

// ws layout (float offsets) — unchanged
#define OFF_XHI  0           // ushort [8][4097][256]
#define OFF_XLO  4195328
#define OFF_WHI  8390656     // ushort [1024][512]
#define OFF_WLO  8652800
#define OFF_F16  8914944     // ushort(f16) [8][4096][256]
#define OFF_IZ16 13109248
#define OFF_O16  17303552
#define OFF_A    21497856    // float [8][128][256]
#define OFF_B    21760000
#define OFF_C    22022144

typedef __attribute__((ext_vector_type(8))) short short8;
typedef __attribute__((ext_vector_type(16))) float floatx16;

__device__ __forceinline__ float fsig(float x)  { return 1.0f / (1.0f + __expf(-x)); }
__device__ __forceinline__ float ftanh(float x) { return 2.0f / (1.0f + __expf(-2.0f * x)) - 1.0f; }

__device__ __forceinline__ unsigned short bf16_rne(float v) {
    unsigned u = __float_as_uint(v);
    unsigned r = (u + 0x7fffu + ((u >> 16) & 1u)) >> 16;
    return (unsigned short)r;
}
__device__ __forceinline__ void split_bf16(float v, unsigned short& hi, unsigned short& lo) {
    hi = bf16_rne(v);
    float hf = __uint_as_float(((unsigned)hi) << 16);
    lo = bf16_rne(v - hf);
}

// async 16B/lane global->LDS DMA; lds base must be wave-uniform (dest = base + lane*16)
__device__ __forceinline__ void glds16(const unsigned short* g, unsigned short* l) {
    __builtin_amdgcn_global_load_lds(
        (const __attribute__((address_space(1))) unsigned*)g,
        (__attribute__((address_space(3))) unsigned*)l, 16, 0, 0);
}

// merged converts: bid<2048 -> W repack/split; bid>=2048 -> X transpose/split.
// W[o=g*256+c][i][j] -> Wa[r=c*4+g][k=j*256+i].  x[b][c][t] -> Xpad[b][t+1][c].
__global__ void convert_kernel(const float* __restrict__ W,
                               const float* __restrict__ x,
                               unsigned short* __restrict__ Whi,
                               unsigned short* __restrict__ Wlo,
                               unsigned short* __restrict__ Xhi,
                               unsigned short* __restrict__ Xlo) {
    __shared__ float tile[64][69];      // 69 mod 32 = 5 -> conflict-free both phases
    const int bid = blockIdx.x;
    const int tid = threadIdx.x;
    if (bid < 2048) {
        int e = bid * 256 + tid;        // 1024*512 elements
        int r = e >> 9, k = e & 511;
        int g = r & 3, c = r >> 2;
        int j = k >> 8, i = k & 255;
        float v = W[((size_t)((g << 8) + c)) * 512 + i * 2 + j];
        unsigned short hi, lo;
        split_bf16(v, hi, lo);
        Whi[e] = hi;
        Wlo[e] = lo;
        return;
    }
    const int b2 = bid - 2048;
    const int t0 = (b2 & 63) * 64;
    const int c0 = ((b2 >> 6) & 3) * 64;
    const int b  = b2 >> 8;

    {   // read: float4 along t, 16 rows per pass
        int j4 = (tid & 15) * 4, r16 = tid >> 4;
#pragma unroll
        for (int p = 0; p < 4; p++) {
            int i = p * 16 + r16;
            float4 v = *(const float4*)&x[((size_t)(b * 256 + c0 + i)) * T_ + t0 + j4];
            tile[i][j4] = v.x; tile[i][j4 + 1] = v.y;
            tile[i][j4 + 2] = v.z; tile[i][j4 + 3] = v.w;
        }
    }
    if (t0 == 0 && tid < 64) {   // zero pad row (x[-1] = 0)
        size_t z = (size_t)b * TP * 256 + c0 + tid;
        Xhi[z] = 0; Xlo[z] = 0;
    }
    __syncthreads();
    {   // write coalesced along c
        int i = tid & 63, jj = tid >> 6;
#pragma unroll
        for (int p = 0; p < 16; p++) {
            int t = jj * 16 + p;
            float v = tile[i][t];
            unsigned short hi, lo;
            split_bf16(v, hi, lo);
            size_t idx = ((size_t)b * TP + t0 + t + 1) * 256 + c0 + i;
            Xhi[idx] = hi;
            Xlo[idx] = lo;
        }
    }
}

// C[r=1024][n=32768] = Wa · Xb^T, split-bf16 (3 products), 256x256 tile,
// 8 waves (2M x 4N), BK=32, 16 K-steps.
// Round 3: (a) mfma_f32_32x32x16_bf16 — half the MFMA instructions, +17%
// pipe ceiling; per wave: 4 m-subtiles x 2 n-subtiles x f32x16 acc.
// (b) both-sides XOR swizzle (k-slot ^= (row&3)*8 ushorts) — DMA source
// pre-swizzled per-lane, reads XOR'd: all 32 banks, 8 accesses each
// (the naive 32-row fragment read uses only 16 banks = 2x conflict).
// (c) m201 phase shape: [ds_reads | stage DMA | counted vmcnt | s_barrier |
// lgkmcnt(0)+sched_barrier | setprio MFMA | s_barrier] — raw s_barrier
// doesn't drain lgkm, so read latency hides under barrier convergence.
// Counted-vmcnt ledger identical to round 2 (verified): 6/6/4.
// LDS planes (ushort idx): AH+0, AL+8192, BH+16384, BL+24576; dbuf +32768.
__launch_bounds__(512, 2)
__global__ void gemm_mfma_kernel(const unsigned short* __restrict__ Xhi,
                                 const unsigned short* __restrict__ Xlo,
                                 const unsigned short* __restrict__ Whi,
                                 const unsigned short* __restrict__ Wlo,
                                 const float* __restrict__ bias,
                                 __half* __restrict__ fw,
                                 __half* __restrict__ izw,
                                 __half* __restrict__ ow,
                                 float* __restrict__ Aw,
                                 float* __restrict__ Bw)
{
    __shared__ unsigned short smem_us[65536];   // 128 KiB

    const int tid  = threadIdx.x;
    const int wave = tid >> 6, lane = tid & 63;
    const int col = lane & 31, q2 = lane >> 5;
    const int wm = wave >> 2, wn = wave & 3;     // 2 x 4 wave grid

    // bijective XCD swizzle: 512 blocks = 8 xcd x (16 n-tiles x 4 r, r fastest)
    const int bid   = blockIdx.x;
    const int xcd   = bid & 7;
    const int idx   = bid >> 3;                  // 0..63
    const int n_blk = xcd * 16 + (idx >> 2);     // 0..127
    const int r_blk = idx & 3;                   // 0..3
    const int r0 = r_blk * 256;
    const int n0 = n_blk * 256;
    const int bb = n0 >> 12;
    const int t0 = n0 & (T_ - 1);

    // staging: wave w stages rows w*32..w*32+31 of each plane; 2 DMAs per plane.
    // Source col pre-swizzled so linear LDS dest holds k-slot ^ (row&3)*8.
    const int lrow = lane >> 2;                        // 0..15
    const int lcol = (((lane & 3) ^ (lrow & 3)) * 8);  // swizzled ushort offset
    const size_t wAoff = (size_t)(r0 + wave * 32 + lrow) * 512 + lcol;
    const unsigned short* pWh0 = Whi + wAoff;
    const unsigned short* pWh1 = pWh0 + 16 * 512;
    const unsigned short* pWl0 = Wlo + wAoff;
    const unsigned short* pWl1 = pWl0 + 16 * 512;
    const size_t xBoff = ((size_t)bb * TP + t0 + wave * 32 + lrow) * 256 + lcol;
    const unsigned short* pXh0 = Xhi + xBoff;
    const unsigned short* pXh1 = pXh0 + 16 * 256;
    const unsigned short* pXl0 = Xlo + xBoff;
    const unsigned short* pXl1 = pXl0 + 16 * 256;

    // fragment read bases (ushort offsets within one plane)
    const int arow = (wm * 128 + col) * 32;      // + ms*1024
    const int brow = (wn * 64  + col) * 32;      // + ns*1024
    const int fswz = (q2 * 8) ^ ((col & 3) * 8); // ^ (ks*16) per k-slice
    const int wst = wave * 1024;                 // wave staging offset in plane

    floatx16 acc[4][2];
#pragma unroll
    for (int ms = 0; ms < 4; ++ms)
#pragma unroll
        for (int ns = 0; ns < 2; ++ns)
#pragma unroll
            for (int e = 0; e < 16; ++e) acc[ms][ns][e] = 0.f;

    // prologue: stage K-step 0 into buffer 0, order AH,BH,BL,AL (oldest first)
    {
        unsigned short* b0 = smem_us;
        glds16(pWh0, b0 + wst);                 glds16(pWh1, b0 + wst + 512);
        glds16(pXh0, b0 + 16384 + wst);         glds16(pXh1, b0 + 16384 + wst + 512);
        glds16(pXl0, b0 + 24576 + wst);         glds16(pXl1, b0 + 24576 + wst + 512);
        glds16(pWl0, b0 + 8192 + wst);          glds16(pWl1, b0 + 8192 + wst + 512);
        asm volatile("s_waitcnt vmcnt(4)" ::: "memory");   // AH,BH landed; BL,AL in flight
        __builtin_amdgcn_s_barrier();
        __builtin_amdgcn_sched_barrier(0);
    }

#pragma unroll 2
    for (int i = 0; i < 16; ++i) {
        const int cur = i & 1, nxt = cur ^ 1;
        const unsigned kk = (unsigned)(((i + 1) & 15) * 32);   // wrap keeps counts uniform
        const unsigned short* AHc = smem_us + cur * 32768;
        const unsigned short* ALc = AHc + 8192;
        const unsigned short* BHc = AHc + 16384;
        const unsigned short* BLc = AHc + 24576;
        unsigned short* dAH = smem_us + nxt * 32768 + wst;
        unsigned short* dAL = dAH + 8192;
        unsigned short* dBH = dAH + 16384;
        unsigned short* dBL = dAH + 24576;

        short8 ah[4][2], bh[2][2];

        // ---------- P0: hi*hi ----------
#pragma unroll
        for (int ms = 0; ms < 4; ++ms)
#pragma unroll
            for (int ks = 0; ks < 2; ++ks)
                ah[ms][ks] = *(const short8*)(AHc + arow + ms * 1024 + (fswz ^ (ks << 4)));
#pragma unroll
        for (int ns = 0; ns < 2; ++ns)
#pragma unroll
            for (int ks = 0; ks < 2; ++ks)
                bh[ns][ks] = *(const short8*)(BHc + brow + ns * 1024 + (fswz ^ (ks << 4)));
        glds16(pWh0 + kk, dAH); glds16(pWh1 + kk, dAH + 512);
        glds16(pXh0 + kk, dBH); glds16(pXh1 + kk, dBH + 512);
        asm volatile("s_waitcnt vmcnt(6)" ::: "memory");   // BL[cur] landed
        __builtin_amdgcn_s_barrier();
        asm volatile("s_waitcnt lgkmcnt(0)" ::: "memory");
        __builtin_amdgcn_sched_barrier(0);
        __builtin_amdgcn_s_setprio(1);
#pragma unroll
        for (int ks = 0; ks < 2; ++ks)
#pragma unroll
            for (int ms = 0; ms < 4; ++ms)
#pragma unroll
                for (int ns = 0; ns < 2; ++ns)
                    acc[ms][ns] = __builtin_amdgcn_mfma_f32_32x32x16_bf16(
                        ah[ms][ks], bh[ns][ks], acc[ms][ns], 0, 0, 0);
        __builtin_amdgcn_s_setprio(0);
        __builtin_amdgcn_s_barrier();

        // ---------- P1: hi*lo ----------
        {
            short8 bl[2][2];
#pragma unroll
            for (int ns = 0; ns < 2; ++ns)
#pragma unroll
                for (int ks = 0; ks < 2; ++ks)
                    bl[ns][ks] = *(const short8*)(BLc + brow + ns * 1024 + (fswz ^ (ks << 4)));
            glds16(pXl0 + kk, dBL); glds16(pXl1 + kk, dBL + 512);
            asm volatile("s_waitcnt vmcnt(6)" ::: "memory");   // AL[cur] landed
            __builtin_amdgcn_s_barrier();
            asm volatile("s_waitcnt lgkmcnt(0)" ::: "memory");
            __builtin_amdgcn_sched_barrier(0);
            __builtin_amdgcn_s_setprio(1);
#pragma unroll
            for (int ks = 0; ks < 2; ++ks)
#pragma unroll
                for (int ms = 0; ms < 4; ++ms)
#pragma unroll
                    for (int ns = 0; ns < 2; ++ns)
                        acc[ms][ns] = __builtin_amdgcn_mfma_f32_32x32x16_bf16(
                            ah[ms][ks], bl[ns][ks], acc[ms][ns], 0, 0, 0);
            __builtin_amdgcn_s_setprio(0);
            __builtin_amdgcn_s_barrier();
        }

        // ---------- P2: lo*hi ----------
        {
            short8 al[4][2];
#pragma unroll
            for (int ms = 0; ms < 4; ++ms)
#pragma unroll
                for (int ks = 0; ks < 2; ++ks)
                    al[ms][ks] = *(const short8*)(ALc + arow + ms * 1024 + (fswz ^ (ks << 4)));
            glds16(pWl0 + kk, dAL); glds16(pWl1 + kk, dAL + 512);
            asm volatile("s_waitcnt vmcnt(4)" ::: "memory");   // AH,BH[nxt] landed
            __builtin_amdgcn_s_barrier();
            asm volatile("s_waitcnt lgkmcnt(0)" ::: "memory");
            __builtin_amdgcn_sched_barrier(0);
            __builtin_amdgcn_s_setprio(1);
#pragma unroll
            for (int ks = 0; ks < 2; ++ks)
#pragma unroll
                for (int ms = 0; ms < 4; ++ms)
#pragma unroll
                    for (int ns = 0; ns < 2; ++ns)
                        acc[ms][ns] = __builtin_amdgcn_mfma_f32_32x32x16_bf16(
                            al[ms][ks], bh[ns][ks], acc[ms][ns], 0, 0, 0);
            __builtin_amdgcn_s_setprio(0);
            __builtin_amdgcn_s_barrier();
        }
    }

    // ---------- epilogue ----------
    asm volatile("s_waitcnt vmcnt(0)" ::: "memory");   // drain wrap-staging junk DMAs
    __syncthreads();                     // LDS reused below
    __half* epf = (__half*)smem_us;      // [256][72] f16
    __half* epz = epf + 256 * 72;
    __half* epo = epz + 256 * 72;        // total 110,592 B < 128 KiB
    const int ch_base = r0 >> 2;         // 64 channels per block

    // 32x32 C/D: col = lane&31 (t), row = (reg&3) + 8*(reg>>2) + 4*q2.
    // gate = reg&3; channel_local = wm*32 + ms*8 + 2*(reg>>2) + q2.
#pragma unroll
    for (int ms = 0; ms < 4; ++ms) {
#pragma unroll
        for (int rg = 0; rg < 4; ++rg) {
            const int cl = wm * 32 + ms * 8 + 2 * rg + q2;   // local channel 0..63
            const int ch = ch_base + cl;
            const float bz  = bias[ch];
            const float bf_ = bias[256 + ch];
            const float bo  = bias[512 + ch];
            const float bi  = bias[768 + ch];
#pragma unroll
            for (int ns = 0; ns < 2; ++ns) {
                const int t_l = wn * 64 + ns * 32 + col;     // local t 0..255
                float zv = ftanh(acc[ms][ns][4 * rg + 0] + bz);
                float fv = fsig(acc[ms][ns][4 * rg + 1] + bf_);
                float ov = fsig(acc[ms][ns][4 * rg + 2] + bo);
                float iv = fsig(acc[ms][ns][4 * rg + 3] + bi);
                const int off = t_l * 72 + cl;
                epf[off] = __float2half(fv);                 // same f16 rounding as before
                epz[off] = __float2half(iv * zv);
                epo[off] = __float2half(ov);
            }
        }
    }
    __syncthreads();

    // coalesced f16 stores: 2 threads per t-row, 32 channels (4x uint4) each
    {
        const int t_r = tid >> 1;                    // 0..255
        const int cb = (tid & 1) << 5;               // 0 or 32
        const size_t gbase = ((size_t)bb * T_ + t0 + t_r) * 256 + ch_base + cb;
        const int lb = t_r * 72 + cb;                // 16B-aligned (144 | 16)
        {
            const uint4* s = (const uint4*)&epf[lb];
            uint4* d = (uint4*)&fw[gbase];
            d[0] = s[0]; d[1] = s[1]; d[2] = s[2]; d[3] = s[3];
        }
        {
            const uint4* s = (const uint4*)&epz[lb];
            uint4* d = (uint4*)&izw[gbase];
            d[0] = s[0]; d[1] = s[1]; d[2] = s[2]; d[3] = s[3];
        }
        {
            const uint4* s = (const uint4*)&epo[lb];
            uint4* d = (uint4*)&ow[gbase];
            d[0] = s[0]; d[1] = s[1]; d[2] = s[2]; d[3] = s[3];
        }
    }

    // fused scan phase 1: per-chunk (A = prod f, B = affine end); 8 chunks x 64 ch
    {
        const int chunk = tid >> 6;                  // 0..7 (== wave)
        const int c = tid & 63;
        float A = 1.0f, Bv = 0.0f;
        const int base = (chunk * 32) * 72 + c;
#pragma unroll 4
        for (int j = 0; j < 32; ++j) {
            float f  = __half2float(epf[base + j * 72]);
            float iz = __half2float(epz[base + j * 72]);
            Bv = fmaf(f, Bv, iz);
            A *= f;
        }
        const int chunk_abs = (t0 >> 5) + chunk;
        const size_t aidx = ((size_t)bb * NCH + chunk_abs) * 256 + ch_base + c;
        Aw[aidx] = A;
        Bw[aidx] = Bv;
    }
}

// Phase 2: exclusive scan over chunk summaries; loads batched 16-wide to pipeline
__global__ void scan_phase2(const float* __restrict__ Aw, const float* __restrict__ Bw,
                            float* __restrict__ cw)
{
    int b = blockIdx.x, c = threadIdx.x;
    float carry = 0.0f;
    for (int ch0 = 0; ch0 < NCH; ch0 += 16) {
        float Ar[16], Br[16], cv[16];
#pragma unroll
        for (int j = 0; j < 16; j++) {
            size_t idx = ((size_t)(b * NCH + ch0 + j)) * CO + c;
            Ar[j] = Aw[idx];
            Br[j] = Bw[idx];
        }
#pragma unroll
        for (int j = 0; j < 16; j++) {
            cv[j] = carry;
            carry = fmaf(Ar[j], carry, Br[j]);
        }
#pragma unroll
        for (int j = 0; j < 16; j++)
            cw[((size_t)(b * NCH + ch0 + j)) * CO + c] = cv[j];
    }
}

// Phase 3: replay recurrence with carry, h = o*c, transpose [t][c] -> out[b][c][t]
__global__ void scan_phase3(const __half* __restrict__ fw, const __half* __restrict__ izw,
                            const __half* __restrict__ ow, const float* __restrict__ cw,
                            float* __restrict__ out)
{
    __shared__ float hbuf[CL][257];
    int b = blockIdx.y, ch = blockIdx.x, c = threadIdx.x;
    float cs = cw[((size_t)(b * NCH + ch)) * CO + c];
    size_t base = ((size_t)(b * T_ + ch * CL)) * CO + c;
#pragma unroll 4
    for (int tt = 0; tt < CL; tt++) {
        float f  = __half2float(fw[base + (size_t)tt * CO]);
        float iz = __half2float(izw[base + (size_t)tt * CO]);
        float o  = __half2float(ow[base + (size_t)tt * CO]);
        cs = fmaf(f, cs, iz);
        hbuf[tt][c] = o * cs;
    }
    __syncthreads();
    int tt = threadIdx.x & 31;
    int cr = threadIdx.x >> 5;
#pragma unroll
    for (int w = 0; w < 32; w++) {
        int cc = cr + w * 8;
        out[((size_t)(b * CO + cc)) * T_ + ch * CL + tt] = hbuf[tt][cc];
    }
}

extern "C" void kernel_launch(void* const* d_in, const int* in_sizes, int n_in,
                              void* d_out, int out_size, void* d_ws, size_t ws_size,
                              hipStream_t stream) {
    const float* x    = (const float*)d_in[0];
    const float* W    = (const float*)d_in[1];
    const float* bias = (const float*)d_in[2];
    float* out = (float*)d_out;
    float* ws  = (float*)d_ws;

    unsigned short* Xhi = (unsigned short*)(ws + OFF_XHI);
    unsigned short* Xlo = (unsigned short*)(ws + OFF_XLO);
    unsigned short* Whi = (unsigned short*)(ws + OFF_WHI);
    unsigned short* Wlo = (unsigned short*)(ws + OFF_WLO);
    __half* fw  = (__half*)(ws + OFF_F16);
    __half* izw = (__half*)(ws + OFF_IZ16);
    __half* ow  = (__half*)(ws + OFF_O16);
    float* Aw  = ws + OFF_A;
    float* Bw  = ws + OFF_B;
    float* cw  = ws + OFF_C;

    convert_kernel<<<4096, 256, 0, stream>>>(W, x, Whi, Wlo, Xhi, Xlo);
    gemm_mfma_kernel<<<(NN / 256) * (O4 / 256), 512, 0, stream>>>(
        Xhi, Xlo, Whi, Wlo, bias, fw, izw, ow, Aw, Bw);
    scan_phase2<<<B_, CO, 0, stream>>>(Aw, Bw, cw);
    scan_phase3<<<dim3(NCH, B_), CO, 0, stream>>>(fw, izw, ow, cw, out);
}

// Round 4
// 211.453 us; speedup vs baseline: 1.0724x; 1.0724x over previous
//
#include <hip/hip_runtime.h>
#include <hip/hip_fp16.h>

#define B_   8
#define CIN  256
#define T_   4096
#define TP   4097    // padded T (row 0 = zeros, row t+1 = x[t])
#define CO   256
#define O4   1024
#define NN   32768   // B_*T_
#define NCH  128     // chunks along T
#define CL   32      // chunk length

// ws layout (float offsets) — unchanged
#define OFF_XHI  0           // ushort [8][4097][256]
#define OFF_XLO  4195328
#define OFF_WHI  8390656     // ushort [1024][512]
#define OFF_WLO  8652800
#define OFF_F16  8914944     // ushort(f16) [8][4096][256]
#define OFF_IZ16 13109248
#define OFF_O16  17303552
#define OFF_A    21497856    // float [8][128][256]
#define OFF_B    21760000
#define OFF_C    22022144

typedef __attribute__((ext_vector_type(8))) short short8;
typedef __attribute__((ext_vector_type(4))) float floatx4;

__device__ __forceinline__ float fsig(float x)  { return 1.0f / (1.0f + __expf(-x)); }
__device__ __forceinline__ float ftanh(float x) { return 2.0f / (1.0f + __expf(-2.0f * x)) - 1.0f; }

__device__ __forceinline__ unsigned short bf16_rne(float v) {
    unsigned u = __float_as_uint(v);
    unsigned r = (u + 0x7fffu + ((u >> 16) & 1u)) >> 16;
    return (unsigned short)r;
}
__device__ __forceinline__ void split_bf16(float v, unsigned short& hi, unsigned short& lo) {
    hi = bf16_rne(v);
    float hf = __uint_as_float(((unsigned)hi) << 16);
    lo = bf16_rne(v - hf);
}

// async 16B/lane global->LDS DMA; lds base must be wave-uniform (dest = base + lane*16)
__device__ __forceinline__ void glds16(const unsigned short* g, unsigned short* l) {
    __builtin_amdgcn_global_load_lds(
        (const __attribute__((address_space(1))) unsigned*)g,
        (__attribute__((address_space(3))) unsigned*)l, 16, 0, 0);
}

// merged converts: bid<2048 -> W repack/split; bid>=2048 -> X transpose/split.
// W[o=g*256+c][i][j] -> Wa[r=c*4+g][k=j*256+i].  x[b][c][t] -> Xpad[b][t+1][c].
__global__ void convert_kernel(const float* __restrict__ W,
                               const float* __restrict__ x,
                               unsigned short* __restrict__ Whi,
                               unsigned short* __restrict__ Wlo,
                               unsigned short* __restrict__ Xhi,
                               unsigned short* __restrict__ Xlo) {
    __shared__ float tile[64][69];      // 69 mod 32 = 5 -> conflict-free both phases
    const int bid = blockIdx.x;
    const int tid = threadIdx.x;
    if (bid < 2048) {
        int e = bid * 256 + tid;        // 1024*512 elements
        int r = e >> 9, k = e & 511;
        int g = r & 3, c = r >> 2;
        int j = k >> 8, i = k & 255;
        float v = W[((size_t)((g << 8) + c)) * 512 + i * 2 + j];
        unsigned short hi, lo;
        split_bf16(v, hi, lo);
        Whi[e] = hi;
        Wlo[e] = lo;
        return;
    }
    const int b2 = bid - 2048;
    const int t0 = (b2 & 63) * 64;
    const int c0 = ((b2 >> 6) & 3) * 64;
    const int b  = b2 >> 8;

    {   // read: float4 along t, 16 rows per pass
        int j4 = (tid & 15) * 4, r16 = tid >> 4;
#pragma unroll
        for (int p = 0; p < 4; p++) {
            int i = p * 16 + r16;
            float4 v = *(const float4*)&x[((size_t)(b * 256 + c0 + i)) * T_ + t0 + j4];
            tile[i][j4] = v.x; tile[i][j4 + 1] = v.y;
            tile[i][j4 + 2] = v.z; tile[i][j4 + 3] = v.w;
        }
    }
    if (t0 == 0 && tid < 64) {   // zero pad row (x[-1] = 0)
        size_t z = (size_t)b * TP * 256 + c0 + tid;
        Xhi[z] = 0; Xlo[z] = 0;
    }
    __syncthreads();
    {   // write: 4 consecutive channels per thread, packed uint2 (8B) stores
        const int cslot = tid & 15, trow = tid >> 4;
#pragma unroll
        for (int p = 0; p < 4; p++) {
            int t = p * 16 + trow;
            unsigned hi0, hi1, lo0, lo1;
            {
                unsigned short h, l;
                split_bf16(tile[cslot * 4 + 0][t], h, l);
                hi0 = h; lo0 = l;
                split_bf16(tile[cslot * 4 + 1][t], h, l);
                hi0 |= ((unsigned)h) << 16; lo0 |= ((unsigned)l) << 16;
                split_bf16(tile[cslot * 4 + 2][t], h, l);
                hi1 = h; lo1 = l;
                split_bf16(tile[cslot * 4 + 3][t], h, l);
                hi1 |= ((unsigned)h) << 16; lo1 |= ((unsigned)l) << 16;
            }
            size_t idx = ((size_t)b * TP + t0 + t + 1) * 256 + c0 + cslot * 4;
            uint2 ph; ph.x = hi0; ph.y = hi1;
            uint2 pl; pl.x = lo0; pl.y = lo1;
            *(uint2*)&Xhi[idx] = ph;
            *(uint2*)&Xlo[idx] = pl;
        }
    }
}

// C[r=1024][n=32768] = Wa · Xb^T, split-bf16 MFMA (3 products).
// Round 4: 128x128 tile, BK=32, 16 K-steps, LDS 64 KiB -> 2 blocks/CU
// (occupancy was the binding constraint: rounds 1-3 all 21% occ, 1 block/CU,
// identical perf across different schedules). 8 waves (2M x 4N), per-wave
// 64x32 output, acc = 8 floatx4 (32 regs). 3-phase counted-vmcnt schedule
// (round-2 proven logic, re-derived for 1 DMA/plane/wave):
//   prologue: issue AH,BH,BL,AL; vmcnt(2)
//   P0 reads AH,BH; issues AH',BH'; MFMA hh; vmcnt(3); barrier
//   P1 reads BL;    issues BL';    MFMA hl; vmcnt(3); barrier
//   P2 reads AL;    issues AL';    MFMA lh; vmcnt(2); barrier
// Epilogue f16 stride 36 (72B rows; 72*t mod 128 distinct for t&15 — kills
// the deterministic 4-way ep-store bank conflict of the old stride-72).
// LDS planes (ushort idx): AH+0, AL+4096, BH+8192, BL+12288; dbuf +16384.
__launch_bounds__(512, 4)
__global__ void gemm_mfma_kernel(const unsigned short* __restrict__ Xhi,
                                 const unsigned short* __restrict__ Xlo,
                                 const unsigned short* __restrict__ Whi,
                                 const unsigned short* __restrict__ Wlo,
                                 const float* __restrict__ bias,
                                 __half* __restrict__ fw,
                                 __half* __restrict__ izw,
                                 __half* __restrict__ ow,
                                 float* __restrict__ Aw,
                                 float* __restrict__ Bw)
{
    __shared__ unsigned short smem_us[32768];   // 64 KiB

    const int tid  = threadIdx.x;
    const int wave = tid >> 6, lane = tid & 63;
    const int q = lane >> 4, mr = lane & 15;
    const int wm = wave >> 2, wn = wave & 3;     // 2 x 4 wave grid (M x N)

    // grid: 2048 = 8 xcd x (32 n-tiles x 8 r, r fastest -> X-tile L2-resident)
    const int bid   = blockIdx.x;
    const int xcd   = bid & 7;
    const int idx   = bid >> 3;                  // 0..255
    const int n_blk = xcd * 32 + (idx >> 3);     // 0..255
    const int r_blk = idx & 7;                   // 0..7
    const int r0 = r_blk * 128;
    const int n0 = n_blk * 128;
    const int bb = n0 >> 12;
    const int t0 = n0 & (T_ - 1);

    // staging: wave w stages rows w*16..w*16+15 of each plane; 1 DMA per plane
    const int lrow = lane >> 2;            // 0..15
    const int lcol = (lane & 3) * 8;       // ushort offset in row
    const size_t wAoff = (size_t)(r0 + wave * 16 + lrow) * 512 + lcol;
    const unsigned short* pWh = Whi + wAoff;
    const unsigned short* pWl = Wlo + wAoff;
    const size_t xBoff = ((size_t)bb * TP + t0 + wave * 16 + lrow) * 256 + lcol;
    const unsigned short* pXh = Xhi + xBoff;
    const unsigned short* pXl = Xlo + xBoff;

    // fragment read bases (ushort offsets within one plane)
    const int aoffb = (wm * 64 + mr) * 32 + q * 8;
    const int boffb = (wn * 32 + mr) * 32 + q * 8;
    const int wst = wave * 512;                  // wave staging offset in plane

    floatx4 acc[4][2];
#pragma unroll
    for (int v = 0; v < 4; v++)
#pragma unroll
        for (int u = 0; u < 2; u++) acc[v][u] = (floatx4){0.f, 0.f, 0.f, 0.f};

    // prologue: stage K-step 0 into buffer 0, order AH,BH,BL,AL (oldest first)
    glds16(pWh, smem_us + wst);
    glds16(pXh, smem_us + 8192 + wst);
    glds16(pXl, smem_us + 12288 + wst);
    glds16(pWl, smem_us + 4096 + wst);
    asm volatile("s_waitcnt vmcnt(2)" ::: "memory");   // AH,BH landed; BL,AL in flight
    __builtin_amdgcn_s_barrier();
    __builtin_amdgcn_sched_barrier(0);

#pragma unroll 2
    for (int i = 0; i < 16; ++i) {
        const int cur = i & 1, nxt = cur ^ 1;
        const unsigned kk = (unsigned)(((i + 1) & 15) * 32);   // wrap keeps counts uniform
        const unsigned short* AHc = smem_us + cur * 16384;
        const unsigned short* ALc = AHc + 4096;
        const unsigned short* BHc = AHc + 8192;
        const unsigned short* BLc = AHc + 12288;
        unsigned short* dAH = smem_us + nxt * 16384 + wst;
        unsigned short* dAL = dAH + 4096;
        unsigned short* dBH = dAH + 8192;
        unsigned short* dBL = dAH + 12288;

        short8 ah[4], bh[2];

        // ---------- P0: hi*hi ----------
#pragma unroll
        for (int v = 0; v < 4; ++v) ah[v] = *(const short8*)(AHc + aoffb + v * 512);
#pragma unroll
        for (int u = 0; u < 2; ++u) bh[u] = *(const short8*)(BHc + boffb + u * 512);
        glds16(pWh + kk, dAH);
        glds16(pXh + kk, dBH);
        asm volatile("s_waitcnt lgkmcnt(0)" ::: "memory");
        __builtin_amdgcn_sched_barrier(0);
        __builtin_amdgcn_s_setprio(1);
#pragma unroll
        for (int v = 0; v < 4; ++v)
#pragma unroll
            for (int u = 0; u < 2; ++u)
                acc[v][u] = __builtin_amdgcn_mfma_f32_16x16x32_bf16(ah[v], bh[u], acc[v][u], 0, 0, 0);
        __builtin_amdgcn_s_setprio(0);
        asm volatile("s_waitcnt vmcnt(3)" ::: "memory");   // BL[cur] landed
        __builtin_amdgcn_s_barrier();
        __builtin_amdgcn_sched_barrier(0);

        // ---------- P1: hi*lo ----------
        {
            short8 bl[2];
#pragma unroll
            for (int u = 0; u < 2; ++u) bl[u] = *(const short8*)(BLc + boffb + u * 512);
            glds16(pXl + kk, dBL);
            asm volatile("s_waitcnt lgkmcnt(0)" ::: "memory");
            __builtin_amdgcn_sched_barrier(0);
            __builtin_amdgcn_s_setprio(1);
#pragma unroll
            for (int v = 0; v < 4; ++v)
#pragma unroll
                for (int u = 0; u < 2; ++u)
                    acc[v][u] = __builtin_amdgcn_mfma_f32_16x16x32_bf16(ah[v], bl[u], acc[v][u], 0, 0, 0);
            __builtin_amdgcn_s_setprio(0);
        }
        asm volatile("s_waitcnt vmcnt(3)" ::: "memory");   // AL[cur] landed
        __builtin_amdgcn_s_barrier();
        __builtin_amdgcn_sched_barrier(0);

        // ---------- P2: lo*hi ----------
        {
            short8 al[4];
#pragma unroll
            for (int v = 0; v < 4; ++v) al[v] = *(const short8*)(ALc + aoffb + v * 512);
            glds16(pWl + kk, dAL);
            asm volatile("s_waitcnt lgkmcnt(0)" ::: "memory");
            __builtin_amdgcn_sched_barrier(0);
            __builtin_amdgcn_s_setprio(1);
#pragma unroll
            for (int v = 0; v < 4; ++v)
#pragma unroll
                for (int u = 0; u < 2; ++u)
                    acc[v][u] = __builtin_amdgcn_mfma_f32_16x16x32_bf16(al[v], bh[u], acc[v][u], 0, 0, 0);
            __builtin_amdgcn_s_setprio(0);
        }
        asm volatile("s_waitcnt vmcnt(2)" ::: "memory");   // AH,BH[nxt] landed
        __builtin_amdgcn_s_barrier();
        __builtin_amdgcn_sched_barrier(0);
    }

    // ---------- epilogue ----------
    asm volatile("s_waitcnt vmcnt(0)" ::: "memory");   // drain wrap-staging junk DMAs
    __syncthreads();                     // LDS reused below
    __half* epf = (__half*)smem_us;      // [128][36] f16, 72B rows (conflict-free t-phase)
    __half* epz = epf + 128 * 36;
    __half* epo = epz + 128 * 36;        // total 27,648 B < 64 KiB
    const int ch_base = r0 >> 2;         // 32 channels per block

#pragma unroll
    for (int v = 0; v < 4; ++v) {
        const int cl = wm * 16 + v * 4 + q;          // local channel 0..31
        const int ch = ch_base + cl;
        const float bz  = bias[ch];
        const float bf_ = bias[256 + ch];
        const float bo  = bias[512 + ch];
        const float bi  = bias[768 + ch];
#pragma unroll
        for (int u = 0; u < 2; ++u) {
            const int t_l = wn * 32 + u * 16 + mr;   // local t 0..127
            float zv = ftanh(acc[v][u][0] + bz);
            float fv = fsig(acc[v][u][1] + bf_);
            float ov = fsig(acc[v][u][2] + bo);
            float iv = fsig(acc[v][u][3] + bi);
            const int off = t_l * 36 + cl;
            epf[off] = __float2half(fv);             // same f16 rounding as before
            epz[off] = __float2half(iv * zv);
            epo[off] = __float2half(ov);
        }
    }
    __syncthreads();

    // coalesced f16 stores: 4 threads per t-row, 8 channels (16B) each
    {
        const int t_r = tid >> 2;                    // 0..127
        const int c8 = (tid & 3) << 3;               // 0,8,16,24
        const size_t gbase = ((size_t)bb * T_ + t0 + t_r) * 256 + ch_base + c8;
        const int lb = t_r * 36 + c8;                // 8B-aligned
        union { uint2 u2[2]; uint4 u4; } pk;
        pk.u2[0] = *(const uint2*)&epf[lb];
        pk.u2[1] = *(const uint2*)&epf[lb + 4];
        *(uint4*)&fw[gbase] = pk.u4;
        pk.u2[0] = *(const uint2*)&epz[lb];
        pk.u2[1] = *(const uint2*)&epz[lb + 4];
        *(uint4*)&izw[gbase] = pk.u4;
        pk.u2[0] = *(const uint2*)&epo[lb];
        pk.u2[1] = *(const uint2*)&epo[lb + 4];
        *(uint4*)&ow[gbase] = pk.u4;
    }

    // fused scan phase 1: per-chunk (A = prod f, B = affine end); 4 chunks x 32 ch
    if (tid < 128) {
        const int chunk = tid >> 5;                  // 0..3
        const int c = tid & 31;
        float A = 1.0f, Bv = 0.0f;
        const int base = (chunk * 32) * 36 + c;
#pragma unroll 4
        for (int j = 0; j < 32; ++j) {
            float f  = __half2float(epf[base + j * 36]);
            float iz = __half2float(epz[base + j * 36]);
            Bv = fmaf(f, Bv, iz);
            A *= f;
        }
        const int chunk_abs = (t0 >> 5) + chunk;
        const size_t aidx = ((size_t)bb * NCH + chunk_abs) * 256 + ch_base + c;
        Aw[aidx] = A;
        Bw[aidx] = Bv;
    }
}

// Phase 2: exclusive scan over chunk summaries; loads batched 16-wide to pipeline
__global__ void scan_phase2(const float* __restrict__ Aw, const float* __restrict__ Bw,
                            float* __restrict__ cw)
{
    int b = blockIdx.x, c = threadIdx.x;
    float carry = 0.0f;
    for (int ch0 = 0; ch0 < NCH; ch0 += 16) {
        float Ar[16], Br[16], cv[16];
#pragma unroll
        for (int j = 0; j < 16; j++) {
            size_t idx = ((size_t)(b * NCH + ch0 + j)) * CO + c;
            Ar[j] = Aw[idx];
            Br[j] = Bw[idx];
        }
#pragma unroll
        for (int j = 0; j < 16; j++) {
            cv[j] = carry;
            carry = fmaf(Ar[j], carry, Br[j]);
        }
#pragma unroll
        for (int j = 0; j < 16; j++)
            cw[((size_t)(b * NCH + ch0 + j)) * CO + c] = cv[j];
    }
}

// Phase 3: replay recurrence with carry, h = o*c, transpose [t][c] -> out[b][c][t]
// Vectorized: 128 threads scan 2 adjacent channels each via __half2 loads (ILP 2).
__global__ void scan_phase3(const __half* __restrict__ fw, const __half* __restrict__ izw,
                            const __half* __restrict__ ow, const float* __restrict__ cw,
                            float* __restrict__ out)
{
    __shared__ float hbuf[CL][257];
    int b = blockIdx.y, ch = blockIdx.x;
    int tid = threadIdx.x;
    if (tid < 128) {
        const int c2 = tid * 2;
        float cs0 = cw[((size_t)(b * NCH + ch)) * CO + c2];
        float cs1 = cw[((size_t)(b * NCH + ch)) * CO + c2 + 1];
        size_t base = ((size_t)(b * T_ + ch * CL)) * CO + c2;
#pragma unroll 4
        for (int tt = 0; tt < CL; tt++) {
            __half2 f2  = *(const __half2*)&fw [base + (size_t)tt * CO];
            __half2 iz2 = *(const __half2*)&izw[base + (size_t)tt * CO];
            __half2 o2  = *(const __half2*)&ow [base + (size_t)tt * CO];
            float2 f  = __half22float2(f2);
            float2 iz = __half22float2(iz2);
            float2 o  = __half22float2(o2);
            cs0 = fmaf(f.x, cs0, iz.x);
            cs1 = fmaf(f.y, cs1, iz.y);
            hbuf[tt][c2]     = o.x * cs0;
            hbuf[tt][c2 + 1] = o.y * cs1;
        }
    }
    __syncthreads();
    int tt = threadIdx.x & 31;
    int cr = threadIdx.x >> 5;
#pragma unroll
    for (int w = 0; w < 32; w++) {
        int cc = cr + w * 8;
        out[((size_t)(b * CO + cc)) * T_ + ch * CL + tt] = hbuf[tt][cc];
    }
}

extern "C" void kernel_launch(void* const* d_in, const int* in_sizes, int n_in,
                              void* d_out, int out_size, void* d_ws, size_t ws_size,
                              hipStream_t stream) {
    const float* x    = (const float*)d_in[0];
    const float* W    = (const float*)d_in[1];
    const float* bias = (const float*)d_in[2];
    float* out = (float*)d_out;
    float* ws  = (float*)d_ws;

    unsigned short* Xhi = (unsigned short*)(ws + OFF_XHI);
    unsigned short* Xlo = (unsigned short*)(ws + OFF_XLO);
    unsigned short* Whi = (unsigned short*)(ws + OFF_WHI);
    unsigned short* Wlo = (unsigned short*)(ws + OFF_WLO);
    __half* fw  = (__half*)(ws + OFF_F16);
    __half* izw = (__half*)(ws + OFF_IZ16);
    __half* ow  = (__half*)(ws + OFF_O16);
    float* Aw  = ws + OFF_A;
    float* Bw  = ws + OFF_B;
    float* cw  = ws + OFF_C;

    convert_kernel<<<4096, 256, 0, stream>>>(W, x, Whi, Wlo, Xhi, Xlo);
    gemm_mfma_kernel<<<(NN / 128) * (O4 / 128), 512, 0, stream>>>(
        Xhi, Xlo, Whi, Wlo, bias, fw, izw, ow, Aw, Bw);
    scan_phase2<<<B_, CO, 0, stream>>>(Aw, Bw, cw);
    scan_phase3<<<dim3(NCH, B_), CO, 0, stream>>>(fw, izw, ow, cw, out);
}